// Round 12
// baseline (95.601 us; speedup 1.0000x reference)
//
#include <hip/hip_runtime.h>
#include <math.h>

// Problem constants (fixed by the reference).
#define BB 4
#define SS 2048
#define DD 16
#define HH 16
#define NM 32  // Taylor moments m = 0..31

#define EXP2(x) __builtin_amdgcn_exp2f(x)
#define LOG2E 1.44269504088896340736f

__constant__ float INVFACT[NM] = {
    1.000000000e+00f, 1.000000000e+00f, 5.000000000e-01f, 1.666666667e-01f,
    4.166666667e-02f, 8.333333333e-03f, 1.388888889e-03f, 1.984126984e-04f,
    2.480158730e-05f, 2.755731922e-06f, 2.755731922e-07f, 2.505210839e-08f,
    2.087675699e-09f, 1.605904384e-10f, 1.147074560e-11f, 7.647163732e-13f,
    4.779477332e-14f, 2.811457254e-15f, 1.561920697e-16f, 8.220635247e-18f,
    4.110317623e-19f, 1.957294106e-20f, 8.896791392e-22f, 3.868170171e-23f,
    1.611737571e-24f, 6.446950284e-26f, 2.479596263e-27f, 9.183689864e-29f,
    3.279889237e-30f, 1.130996289e-31f, 3.769987629e-33f, 1.216125042e-34f};

#define UNPACK16(X4, XR)                                                   \
  const float4 x0_ = (X4)[0], x1_ = (X4)[1], x2_ = (X4)[2], x3_ = (X4)[3]; \
  const float XR[16] = {x0_.x, x0_.y, x0_.z, x0_.w, x1_.x, x1_.y, x1_.z,   \
                        x1_.w, x2_.x, x2_.y, x2_.z, x2_.w, x3_.x, x3_.y,   \
                        x3_.z, x3_.w};

// ---------------------------------------------------------------------------
// Kernel M: per-(bh, j-block) moment sums with 1/m! PREFOLDED:
// MT[bh][jb][m]    = (sum_j k_j^m) / m!
// MT[bh][jb][32+m] = (sum_j k_j^m v_j) / m!     (j in block jb, m = 0..31)
// grid = 64 bh x 4 sub = 256 blocks x 256 thr. Block covers 8 j-blocks
// (512 j's): stage k,v in LDS, then thread (jl = t>>5, m = t&31) reduces
// its j-block. k^m via exp-by-squaring with per-lane bit selects.
// ---------------------------------------------------------------------------
__global__ __launch_bounds__(256) void moment_kernel(
    const float* __restrict__ x, const float* __restrict__ w_qkv,
    const float* __restrict__ b_qkv, float* __restrict__ MT) {
  __shared__ float kl[512];
  __shared__ float vl[512];
  const int blk = blockIdx.x;
  const int sub = blk & 3;
  const int bh = blk >> 2;
  const int b = bh >> 4, h = bh & 15;
  const int t = threadIdx.x;

  float wk[16], wv[16];  // block-uniform -> scalar loads
#pragma unroll
  for (int i = 0; i < 16; ++i) {
    wk[i] = w_qkv[i * 48 + 16 + h];
    wv[i] = w_qkv[i * 48 + 32 + h];
  }
  const float bk = b_qkv[16 + h], bv = b_qkv[32 + h];

#pragma unroll
  for (int rr = 0; rr < 2; ++rr) {
    const int jl = rr * 256 + t;  // local j 0..511
    const int j = sub * 512 + jl;
    const float4* X4 = (const float4*)(x + ((size_t)b * SS + j) * DD);
    UNPACK16(X4, xr);
    float k = bk, v = bv;
#pragma unroll
    for (int i = 0; i < 16; ++i) {
      k = fmaf(xr[i], wk[i], k);
      v = fmaf(xr[i], wv[i], v);
    }
    kl[jl] = k;
    vl[jl] = v;
  }
  __syncthreads();

  const int m = t & 31;
  const int jl = t >> 5;        // 0..7
  const int jb = sub * 8 + jl;  // global j-block 0..31
  float s = 0.f, tv = 0.f;
  const int base = jl * 64;
  for (int u = 0; u < 64; ++u) {
    const float k = kl[base + u];  // broadcast across the 32 m-threads
    const float v = vl[base + u];
    const float k2 = k * k, k4 = k2 * k2, k8 = k4 * k4, k16 = k8 * k8;
    float p = (m & 1) ? k : 1.f;
    p *= (m & 2) ? k2 : 1.f;
    p *= (m & 4) ? k4 : 1.f;
    p *= (m & 8) ? k8 : 1.f;
    p *= (m & 16) ? k16 : 1.f;
    s += p;
    tv = fmaf(p, v, tv);
  }
  const float c = INVFACT[m];
  float* row = MT + ((size_t)bh * 32 + jb) * 64;
  row[m] = s * c;
  row[32 + m] = tv * c;
}

// ---------------------------------------------------------------------------
// Kernel B: fused attention (moments + exact diagonal) + output projection.
// grid = 4 b x 32 qb = 128 blocks x 256 thr (4 waves). Lane = query
// s_local; wave w handles heads h = 4w + hh, hh = 0..3 (x row loaded once
// per lane, reused). Per (wave, h): q,k,v via scalar weights; moment prefix
// row (coalesced loads, 1/m! prefolded); exact lane-predicated diagonal;
// AO -> LDS [64 rows][16 h]. Then block projects: out = AO @ w_out + b_out,
// coalesced stores. No AO global round-trip.
// ---------------------------------------------------------------------------
__global__ __launch_bounds__(256) void attn_proj_kernel(
    const float* __restrict__ x, const float* __restrict__ w_qkv,
    const float* __restrict__ b_qkv, const float* __restrict__ MT,
    const float* __restrict__ w_out, const float* __restrict__ b_out,
    float* __restrict__ out) {
  __shared__ float wct[DD * 68];  // w_out column d at wct[d*68 + i]
  __shared__ float bso[DD];
  __shared__ float bc[4][64];     // per-wave: [2m]=S_m/m!, [2m+1]=T_m/m!
  __shared__ float kd[4][64];     // per-wave diagonal k
  __shared__ float vd[4][64];     // per-wave diagonal v
  __shared__ float aol[64 * 16];  // aol[row_l*16 + h]
  const int blk = blockIdx.x;
  const int qb = blk & 31;
  const int b = blk >> 5;
  const int t = threadIdx.x;
  const int w = __builtin_amdgcn_readfirstlane(t >> 6);
  const int lane = t & 63;

  wct[(t & 15) * 68 + (t >> 4)] = w_out[t];  // 256 elements, coalesced
  if (t < DD) bso[t] = b_out[t];

  // x row for this lane's query (shared across this wave's 4 heads).
  const int i0 = qb * 64 + lane;
  const float4* X4 = (const float4*)(x + ((size_t)b * SS + i0) * DD);
  UNPACK16(X4, xr);

#pragma unroll
  for (int hh = 0; hh < 4; ++hh) {
    const int h = w * 4 + hh;  // wave-uniform
    const int bh = b * HH + h;

    float q = b_qkv[h], k = b_qkv[16 + h], v = b_qkv[32 + h];
#pragma unroll
    for (int i = 0; i < 16; ++i) {  // wave-uniform weights -> s_load
      q = fmaf(xr[i], w_qkv[i * 48 + h], q);
      k = fmaf(xr[i], w_qkv[i * 48 + 16 + h], k);
      v = fmaf(xr[i], w_qkv[i * 48 + 32 + h], v);
    }
    kd[w][lane] = k;
    vd[w][lane] = v;

    // Moment prefix row over jb < qb (coalesced; 1/m! already folded).
    if (qb > 0) {
      const float* mtb = MT + (size_t)bh * 32 * 64 + lane;
      float acc = 0.f;
      for (int jb = 0; jb < qb; ++jb) acc += mtb[jb * 64];
      const int slot = (lane < 32) ? (2 * lane) : (2 * (lane - 32) + 1);
      bc[w][slot] = acc;
    }
    __syncthreads();  // uniform trip count: legal; makes kd/vd/bc visible

    float num = 0.f, den = 0.f;
    if (qb > 0) {
      const float2* bc2 = (const float2*)bc[w];
      float p = 1.f;  // q^m
#pragma unroll
      for (int m = 0; m < NM; ++m) {
        const float2 st = bc2[m];  // broadcast read
        den = fmaf(p, st.x, den);
        num = fmaf(p, st.y, num);
        p *= q;
      }
    }

    // Exact diagonal block (lane-predicated: j_local <= lane).
    const float qs = q * LOG2E;
    float ld = 0.f, ad = 0.f;
    const float4* kd4 = (const float4*)kd[w];
    const float4* vd4 = (const float4*)vd[w];
#pragma unroll
    for (int g = 0; g < 16; ++g) {
      const float4 k4 = kd4[g], v4 = vd4[g];
      const int jj = 4 * g;
      float e;
      e = EXP2(qs * k4.x); e = (jj + 0 <= lane) ? e : 0.f; ld += e; ad = fmaf(e, v4.x, ad);
      e = EXP2(qs * k4.y); e = (jj + 1 <= lane) ? e : 0.f; ld += e; ad = fmaf(e, v4.y, ad);
      e = EXP2(qs * k4.z); e = (jj + 2 <= lane) ? e : 0.f; ld += e; ad = fmaf(e, v4.z, ad);
      e = EXP2(qs * k4.w); e = (jj + 3 <= lane) ? e : 0.f; ld += e; ad = fmaf(e, v4.w, ad);
    }

    aol[lane * 16 + h] = (ad + num) / (ld + den);
    __syncthreads();  // uniform; protects kd/vd/bc reuse next hh iteration
  }

  // --- Projection: out[b][s][d], s = qb*64 + row_l. 1024 outputs, 4/thread.
#pragma unroll
  for (int rep = 0; rep < 4; ++rep) {
    const int e = rep * 256 + t;
    const int row_l = e >> 4, d = e & 15;
    const float4* ao4 = (const float4*)(aol + row_l * 16);
    const float4* wc4 = (const float4*)(wct + d * 68);
    float y = bso[d];
#pragma unroll
    for (int g = 0; g < 4; ++g) {
      const float4 xv = ao4[g];
      const float4 wv = wc4[g];
      y = fmaf(xv.x, wv.x, y);
      y = fmaf(xv.y, wv.y, y);
      y = fmaf(xv.z, wv.z, y);
      y = fmaf(xv.w, wv.w, y);
    }
    out[((size_t)b * SS + qb * 64) * DD + e] = y;  // coalesced
  }
}

// ---------------------------------------------------------------------------
extern "C" void kernel_launch(void* const* d_in, const int* in_sizes, int n_in,
                              void* d_out, int out_size, void* d_ws,
                              size_t ws_size, hipStream_t stream) {
  const float* x = (const float*)d_in[0];       // [B,S,D]
  const float* w_qkv = (const float*)d_in[1];   // [D, 3D]
  const float* b_qkv = (const float*)d_in[2];   // [3D]
  const float* w_out = (const float*)d_in[3];   // [D, D]
  const float* b_out = (const float*)d_in[4];   // [D]
  float* out = (float*)d_out;                   // [B,S,D] fp32

  float* MT = (float*)d_ws;  // [64 bh][32 jb][64] prefolded moments (512 KB)

  moment_kernel<<<256, 256, 0, stream>>>(x, w_qkv, b_qkv, MT);
  attn_proj_kernel<<<128, 256, 0, stream>>>(x, w_qkv, b_qkv, MT, w_out,
                                            b_out, out);
}